// Round 1
// baseline (122.205 us; speedup 1.0000x reference)
//
#include <hip/hip_runtime.h>

#define HH 448
#define WW 608
#define CC 64
#define S1 32
#define S2 16
#define HW (HH * WW)
#define BLK 512

// LDS layout for w2 row-slice: element (k, c, k2) stored at word
//   row*32 + (k ^ ((row>>2)&31)),  row = c*16 + k2
// - staging writes (coalesced float4 over k2, k uniform per wave): bank = k ^ (lane&31) -> conflict-free
// - stage-2 reads (row uniform, k = per-lane class): bank = k ^ const -> conflict-free / broadcast

__launch_bounds__(BLK, 1)
__global__ void reg2stage_kernel(const float* __restrict__ x,
                                 const float* __restrict__ w1,
                                 const float* __restrict__ b1,
                                 const float* __restrict__ w2,
                                 const float* __restrict__ b2,
                                 const float* __restrict__ w3,
                                 const float* __restrict__ b3,
                                 float* __restrict__ out) {
    __shared__ float w2s[S1 * CC * S2];   // 32768 floats = 128 KB
    __shared__ float b2s[S1 * S2];        // 512 floats   = 2 KB

    const int h = blockIdx.x;
    const int tid = threadIdx.x;

    // ---- stage w2 row slice into LDS (swizzled) ----
    const float* __restrict__ w2row = w2 + (size_t)h * (S1 * CC * S2);
    for (int e4 = tid; e4 < (S1 * CC * S2) / 4; e4 += BLK) {
        const float4 v = reinterpret_cast<const float4*>(w2row)[e4];
        const int e = e4 * 4;
        const int k = e >> 10;          // class index 0..31
        const int c = (e >> 4) & 63;    // channel
        const int k2 = e & 15;          // k2 base (multiple of 4)
        float vv[4] = {v.x, v.y, v.z, v.w};
#pragma unroll
        for (int j = 0; j < 4; ++j) {
            const int row = c * 16 + k2 + j;
            w2s[row * 32 + (k ^ ((row >> 2) & 31))] = vv[j];
        }
    }
    // b2s[k2*32 + k]  (lanes vary k on read -> conflict-free)
    {
        const int k = tid >> 4, k2 = tid & 15;   // tid < 512 == S1*S2
        b2s[k2 * 32 + k] = b2[((size_t)h * S1 + k) * S2 + k2];
    }
    __syncthreads();

    const float* __restrict__ w1r = w1 + (size_t)h * (S1 * CC);
    const float* __restrict__ b1r = b1 + (size_t)h * S1;

    for (int w = tid; w < WW; w += BLK) {
        // ---- load the pixel's channel vector into registers ----
        float xv[CC];
        const float* __restrict__ xp = x + (size_t)h * WW + w;
#pragma unroll
        for (int c = 0; c < CC; ++c) xv[c] = xp[(size_t)c * HW];

        // ---- stage 1: per-row GEMV + argmax (weights wave-uniform -> s_loads) ----
        float best1 = -INFINITY;
        int k1 = 0;
        for (int k = 0; k < S1; ++k) {
            float acc = b1r[k];
            const float* __restrict__ wk = w1r + k * CC;
#pragma unroll
            for (int c = 0; c < CC; ++c) acc += xv[c] * wk[c];
            if (acc > best1) { best1 = acc; k1 = k; }
        }

        // ---- stage 2: per-pixel (C x S2) matvec from LDS + argmax ----
        float acc2[S2];
#pragma unroll
        for (int k2 = 0; k2 < S2; ++k2) acc2[k2] = b2s[k2 * 32 + k1];
#pragma unroll
        for (int c = 0; c < CC; ++c) {
            const float xc = xv[c];
#pragma unroll
            for (int k2 = 0; k2 < S2; ++k2) {
                const int row = c * 16 + k2;
                acc2[k2] += xc * w2s[row * 32 + (k1 ^ ((row >> 2) & 31))];
            }
        }
        float best2 = -INFINITY;
        int k2b = 0;
#pragma unroll
        for (int k2 = 0; k2 < S2; ++k2) {
            if (acc2[k2] > best2) { best2 = acc2[k2]; k2b = k2; }
        }

        // ---- stage 3: per-pixel (C x 2) matvec, gathered from global ----
        const size_t ind2 = ((size_t)h * S1 + k1) * S2 + k2b;
        const float4* __restrict__ w3p = reinterpret_cast<const float4*>(w3 + ind2 * (CC * 2));
        float r0 = b3[ind2 * 2];
        float r1 = b3[ind2 * 2 + 1];
#pragma unroll
        for (int j = 0; j < 32; ++j) {
            const float4 q = w3p[j];          // covers channels 2j, 2j+1
            r0 += xv[2 * j] * q.x + xv[2 * j + 1] * q.z;
            r1 += xv[2 * j] * q.y + xv[2 * j + 1] * q.w;
        }

        const int loc = k1 * S2 + k2b;        // inds2 - h*S1*S2
        const float x_out = ((float)loc + r0) * 0.5f;
        const float mask = (r1 >= 0.0f) ? r1 : 0.01f * r1;

        out[(size_t)h * WW + w] = x_out;
        out[(size_t)HW + (size_t)h * WW + w] = mask;
    }
}

extern "C" void kernel_launch(void* const* d_in, const int* in_sizes, int n_in,
                              void* d_out, int out_size, void* d_ws, size_t ws_size,
                              hipStream_t stream) {
    const float* x  = (const float*)d_in[0];
    const float* w1 = (const float*)d_in[1];
    const float* b1 = (const float*)d_in[2];
    const float* w2 = (const float*)d_in[3];
    const float* b2 = (const float*)d_in[4];
    const float* w3 = (const float*)d_in[5];
    const float* b3 = (const float*)d_in[6];
    float* out = (float*)d_out;

    reg2stage_kernel<<<dim3(HH), dim3(BLK), 0, stream>>>(x, w1, b1, w2, b2, w3, b3, out);
}

// Round 2
// 84.538 us; speedup vs baseline: 1.4456x; 1.4456x over previous
//
#include <hip/hip_runtime.h>

#define HH 448
#define WW 608
#define CC 64
#define S1 32
#define S2 16
#define HW (HH * WW)
#define BLK 640
#define W2N (S1 * CC * S2)   // 32768 floats = 128 KB
#define W2N4 (W2N / 4)       // 8192 float4
#define NSTG 13              // ceil(8192 / 640)

// LDS layout for w2: element (k, c, k2) at word  k*1024 + k2*64 + (c ^ ((k&15)<<2))
// - stage-2 reads: lanes share (k2, c-quad), differ in k1 -> bank = (4*c4 ^ (k1&7)<<2)%32,
//   8 distinct 4-bank groups -> balanced b128 service (same-k1 lanes broadcast).
// - XOR by multiple of 4 keeps c-quads contiguous -> ds_read_b128 legal.

__launch_bounds__(BLK, 3)
__global__ void reg2stage_kernel(const float* __restrict__ x,
                                 const float* __restrict__ w1,
                                 const float* __restrict__ b1,
                                 const float* __restrict__ w2,
                                 const float* __restrict__ b2,
                                 const float* __restrict__ w3,
                                 const float* __restrict__ b3,
                                 float* __restrict__ out) {
    __shared__ float w2s[W2N];        // 128 KB
    __shared__ float b2s[S1 * S2];    // 2 KB

    const int h = blockIdx.x;
    const int tid = threadIdx.x;
    const int w = tid;                // one pixel per thread; tid >= WW: staging only
    const bool active = (w < WW);

    // ---- issue pixel channel-vector loads early ----
    float xv[CC];
    if (active) {
        const float* __restrict__ xp = x + (size_t)h * WW + w;
#pragma unroll
        for (int c = 0; c < CC; ++c) xv[c] = xp[(size_t)c * HW];
    }

    // ---- issue w2 staging loads into registers (latency hidden under stage 1) ----
    const float4* __restrict__ w2row4 =
        reinterpret_cast<const float4*>(w2 + (size_t)h * W2N);
    float4 stg[NSTG];
#pragma unroll
    for (int i = 0; i < NSTG; ++i) {
        const int e4 = tid + i * BLK;
        if (e4 < W2N4) stg[i] = w2row4[e4];
    }
    float b2v = 0.0f;
    if (tid < S1 * S2) b2v = b2[(size_t)h * (S1 * S2) + tid];   // tid = k*16 + k2

    // ---- stage 1: per-row GEMV + argmax (w1 wave-uniform -> s_loads) ----
    const float* __restrict__ w1r = w1 + (size_t)h * (S1 * CC);
    const float* __restrict__ b1r = b1 + (size_t)h * S1;
    float best1 = -INFINITY;
    int k1 = 0;
    if (active) {
        for (int k = 0; k < S1; ++k) {
            float acc = b1r[k];
            const float* __restrict__ wk = w1r + k * CC;
#pragma unroll
            for (int c = 0; c < CC; ++c) acc += xv[c] * wk[c];
            if (acc > best1) { best1 = acc; k1 = k; }
        }
    }

    // ---- write staged w2 to LDS (swizzled) ----
#pragma unroll
    for (int i = 0; i < NSTG; ++i) {
        const int e4 = tid + i * BLK;
        if (e4 < W2N4) {
            const int e = e4 * 4;
            const int k = e >> 10;            // class
            const int c = (e >> 4) & 63;      // channel
            const int k2b = e & 15;           // k2 base {0,4,8,12}
            const int cx = c ^ ((k & 15) << 2);
            const float vv[4] = {stg[i].x, stg[i].y, stg[i].z, stg[i].w};
#pragma unroll
            for (int j = 0; j < 4; ++j)
                w2s[k * 1024 + (k2b + j) * 64 + cx] = vv[j];
        }
    }
    if (tid < S1 * S2) {
        const int k = tid >> 4, k2 = tid & 15;
        b2s[k2 * 32 + k] = b2v;               // lanes vary k on read -> conflict-free
    }
    __syncthreads();

    if (!active) return;

    // ---- stage 2: (C x S2) matvec from LDS via ds_read_b128 over c-quads ----
    float acc2[S2];
#pragma unroll
    for (int k2 = 0; k2 < S2; ++k2) acc2[k2] = b2s[k2 * 32 + k1];

    const int cxor = (k1 & 15) << 2;
    const float4* __restrict__ w2s4 = reinterpret_cast<const float4*>(w2s);
#pragma unroll
    for (int c4 = 0; c4 < 16; ++c4) {
        const float x0 = xv[4 * c4], x1 = xv[4 * c4 + 1];
        const float x2 = xv[4 * c4 + 2], x3 = xv[4 * c4 + 3];
        const int cg = (4 * c4) ^ cxor;       // swizzled c-quad base (still aligned)
#pragma unroll
        for (int k2 = 0; k2 < S2; ++k2) {
            const float4 q = w2s4[(k1 * 1024 + k2 * 64 + cg) >> 2];
            acc2[k2] += x0 * q.x + x1 * q.y + x2 * q.z + x3 * q.w;
        }
    }
    float best2 = -INFINITY;
    int k2b = 0;
#pragma unroll
    for (int k2 = 0; k2 < S2; ++k2) {
        if (acc2[k2] > best2) { best2 = acc2[k2]; k2b = k2; }
    }

    // ---- stage 3: per-pixel (C x 2) matvec gathered from global (L2/L3 resident) ----
    const size_t ind2 = ((size_t)h * S1 + k1) * S2 + k2b;
    const float4* __restrict__ w3p =
        reinterpret_cast<const float4*>(w3 + ind2 * (CC * 2));
    float r0 = b3[ind2 * 2];
    float r1 = b3[ind2 * 2 + 1];
#pragma unroll
    for (int j = 0; j < 32; ++j) {
        const float4 q = w3p[j];              // channels 2j, 2j+1
        r0 += xv[2 * j] * q.x + xv[2 * j + 1] * q.z;
        r1 += xv[2 * j] * q.y + xv[2 * j + 1] * q.w;
    }

    const int loc = k1 * S2 + k2b;            // inds2 - h*S1*S2
    const float x_out = ((float)loc + r0) * 0.5f;
    const float mask = (r1 >= 0.0f) ? r1 : 0.01f * r1;

    out[(size_t)h * WW + w] = x_out;
    out[(size_t)HW + (size_t)h * WW + w] = mask;
}

extern "C" void kernel_launch(void* const* d_in, const int* in_sizes, int n_in,
                              void* d_out, int out_size, void* d_ws, size_t ws_size,
                              hipStream_t stream) {
    const float* x  = (const float*)d_in[0];
    const float* w1 = (const float*)d_in[1];
    const float* b1 = (const float*)d_in[2];
    const float* w2 = (const float*)d_in[3];
    const float* b2 = (const float*)d_in[4];
    const float* w3 = (const float*)d_in[5];
    const float* b3 = (const float*)d_in[6];
    float* out = (float*)d_out;

    reg2stage_kernel<<<dim3(HH), dim3(BLK), 0, stream>>>(x, w1, b1, w2, b2, w3, b3, out);
}